// Round 8
// baseline (148.876 us; speedup 1.0000x reference)
//
#include <hip/hip_runtime.h>

#define NN 6144
#define DD 768
#define NB 48               // 6144 / 128 tile blocks per dim
#define NTILES 1176         // NB*(NB+1)/2 upper-triangular tiles
#define INV_T 14.285714285714286f
#define CMAX  14.285714285714286f

typedef int i32x8 __attribute__((ext_vector_type(8)));
typedef float f32x4_t __attribute__((ext_vector_type(4)));

// Kernel 1: L2-normalize rows -> fp8 e4m3 (unit MX scale); zero den/num sums.
// One wave per row; 1536 blocks x 256 threads.
__global__ void norm_kernel(const float* __restrict__ feats,
                            unsigned int* __restrict__ fb8,   // 6144*192 uints
                            float* __restrict__ den_num) {    // [0..NN)=den, [NN..2NN)=num
    const int wid = threadIdx.x >> 6;
    const int lane = threadIdx.x & 63;
    const int row = blockIdx.x * 4 + wid;

    if (threadIdx.x < 8) den_num[blockIdx.x * 8 + threadIdx.x] = 0.0f;

    const float4* src = (const float4*)(feats + (size_t)row * DD);
    float4 v[3];
    float ss = 0.0f;
#pragma unroll
    for (int i = 0; i < 3; ++i) {
        v[i] = src[lane + i * 64];
        ss += v[i].x * v[i].x + v[i].y * v[i].y + v[i].z * v[i].z + v[i].w * v[i].w;
    }
#pragma unroll
    for (int m = 32; m >= 1; m >>= 1) ss += __shfl_xor(ss, m);
    const float sc = 1.0f / fmaxf(sqrtf(ss), 1e-12f);

#pragma unroll
    for (int i = 0; i < 3; ++i) {
        unsigned int w = 0;
        w = __builtin_amdgcn_cvt_pk_fp8_f32(v[i].x * sc, v[i].y * sc, w, 0);
        w = __builtin_amdgcn_cvt_pk_fp8_f32(v[i].z * sc, v[i].w * sc, w, 1);
        fb8[(size_t)row * 192 + lane + i * 64] = w;
    }
}

// Kernel 2: upper-triangular MX-fp8 MFMA Gram tiles + fused exp row/col sums.
// NO LDS, NO barriers: the 16x16x128 A/B fragment layout is row-major 32
// contiguous bytes per lane (row=lane&15, k-chunk=lane>>4), so fragments
// load straight from global (L2-resident, fb8=4.7MB) into VGPRs. r6/r7's
// LDS version was serialized by per-iter vmcnt(0)+barrier phase chains
// (~40us vs 6.3us MFMA floor, all pipes <10%); waves now free-run.
// __launch_bounds__(256,2): 256-reg budget, ~115 used -> no spill (r3/r4
// spilled under tighter caps); occupancy is usage-driven (no LDS limit).
// #pragma unroll 1: full unroll of the 6-trip loop interleaves all
// iterations' fragments -> 185-344 MB scratch spill (r3/r4 post-mortems).
__global__ __launch_bounds__(256, 2) void gemm_expsum_kernel(
        const unsigned char* __restrict__ fb8,
        float* __restrict__ den_sum, float* __restrict__ num_sum) {
    // triangular index -> (bi, bj), bi <= bj
    int rem = blockIdx.x;
    int bi = 0, rowlen = NB;
    while (rem >= rowlen) { rem -= rowlen; rowlen--; bi++; }
    const int bj = bi + rem;
    const bool isdiag = (bi == bj);
    const bool neardiag = (bj - bi) <= 1;
    const int i0 = bi * 128;
    const int j0 = bj * 128;

    const int t = threadIdx.x;
    const int lane = t & 63;
    const int wid = t >> 6;
    const int wm = wid >> 1;  // wave row (0..1)
    const int wn = wid & 1;   // wave col (0..1)

    const int q = lane >> 4;      // k-chunk selector (32B each)
    const int mrow = lane & 15;   // fragment row

    // per-lane fragment base pointers (A rows i0.., B rows j0..)
    const unsigned char* pA = fb8 + (size_t)(i0 + wm * 64 + mrow) * DD + q * 32;
    const unsigned char* pB = fb8 + (size_t)(j0 + wn * 64 + mrow) * DD + q * 32;

    f32x4_t acc[4][4];
    const f32x4_t zz = {0.0f, 0.0f, 0.0f, 0.0f};
#pragma unroll
    for (int mi = 0; mi < 4; ++mi)
#pragma unroll
        for (int ni = 0; ni < 4; ++ni) acc[mi][ni] = zz;

#pragma unroll 1
    for (int kb = 0; kb < 6; ++kb) {
        const int k0 = kb * 128;
        i32x8 af[4];
#pragma unroll
        for (int mi = 0; mi < 4; ++mi)
            af[mi] = *(const i32x8*)(pA + (size_t)mi * 16 * DD + k0);
#pragma unroll
        for (int ni = 0; ni < 4; ++ni) {
            const i32x8 bf = *(const i32x8*)(pB + (size_t)ni * 16 * DD + k0);
#pragma unroll
            for (int mi = 0; mi < 4; ++mi)
                acc[mi][ni] = __builtin_amdgcn_mfma_scale_f32_16x16x128_f8f6f4(
                    af[mi], bf, acc[mi][ni], 0, 0,
                    0, 0x7F7F7F7F, 0, 0x7F7F7F7F);  // unit scales (E8M0=127)
        }
    }

    // Epilogue. C/D layout: col=lane&15 (+ni*16), row=(lane>>4)*4+reg (+mi*16).
    const int colb = j0 + wn * 64 + mrow;
    const int rowb = i0 + wm * 64 + (q << 2);
    float cs[4] = {0.f, 0.f, 0.f, 0.f};
    float csn[4] = {0.f, 0.f, 0.f, 0.f};
#pragma unroll
    for (int mi = 0; mi < 4; ++mi) {
        float rsv[4] = {0.f, 0.f, 0.f, 0.f};
        float rsn[4] = {0.f, 0.f, 0.f, 0.f};
#pragma unroll
        for (int ni = 0; ni < 4; ++ni) {
            const int col = colb + ni * 16;
#pragma unroll
            for (int r = 0; r < 4; ++r) {
                const int row = rowb + mi * 16 + r;
                const float v = acc[mi][ni][r] * INV_T;
                float e = __expf(v - CMAX);
                if (isdiag && row == col) e = 0.0f;
                rsv[r] += e;
                cs[ni] += e;
                if (neardiag && (row / 3 == col / 3) && row != col) {
                    rsn[r] += e;
                    csn[ni] += e;
                }
            }
        }
#pragma unroll
        for (int r = 0; r < 4; ++r) {
            float v = rsv[r];
            v += __shfl_xor(v, 8);
            v += __shfl_xor(v, 4);
            v += __shfl_xor(v, 2);
            v += __shfl_xor(v, 1);
            if (mrow == 0) atomicAdd(&den_sum[rowb + mi * 16 + r], v);
        }
        if (neardiag) {
#pragma unroll
            for (int r = 0; r < 4; ++r) {
                float v = rsn[r];
                v += __shfl_xor(v, 8);
                v += __shfl_xor(v, 4);
                v += __shfl_xor(v, 2);
                v += __shfl_xor(v, 1);
                if (mrow == 0) atomicAdd(&num_sum[rowb + mi * 16 + r], v);
            }
        }
    }
    if (!isdiag) {
#pragma unroll
        for (int ni = 0; ni < 4; ++ni) {
            float v = cs[ni];
            v += __shfl_xor(v, 16);
            v += __shfl_xor(v, 32);
            if (q == 0) atomicAdd(&den_sum[colb + ni * 16], v);
        }
        if (neardiag) {
#pragma unroll
            for (int ni = 0; ni < 4; ++ni) {
                float v = csn[ni];
                v += __shfl_xor(v, 16);
                v += __shfl_xor(v, 32);
                if (q == 0) atomicAdd(&num_sum[colb + ni * 16], v);
            }
        }
    }
}

// Kernel 3: loss = mean(log(den) - log(num))  (CMAX cancels). Single block.
__global__ void finalize_kernel(const float* __restrict__ den_sum,
                                const float* __restrict__ num_sum,
                                float* __restrict__ out) {
    float local = 0.0f;
    for (int i = threadIdx.x; i < NN; i += 256) {
        local += logf(den_sum[i]) - logf(num_sum[i]);
    }
#pragma unroll
    for (int m = 32; m >= 1; m >>= 1) local += __shfl_xor(local, m);
    __shared__ float ws[4];
    if ((threadIdx.x & 63) == 0) ws[threadIdx.x >> 6] = local;
    __syncthreads();
    if (threadIdx.x == 0) out[0] = (ws[0] + ws[1] + ws[2] + ws[3]) / (float)NN;
}

extern "C" void kernel_launch(void* const* d_in, const int* in_sizes, int n_in,
                              void* d_out, int out_size, void* d_ws, size_t ws_size,
                              hipStream_t stream) {
    const float* feats = (const float*)d_in[0];
    float* out = (float*)d_out;

    char* ws = (char*)d_ws;
    unsigned int* fb8 = (unsigned int*)ws;                 // 6144*768 = 4718592 B
    float* den_num    = (float*)(ws + 4718592);            // 2*6144*4 B
    float* den_sum    = den_num;
    float* num_sum    = den_num + NN;

    norm_kernel<<<NN / 4, 256, 0, stream>>>(feats, fb8, den_num);
    gemm_expsum_kernel<<<NTILES, 256, 0, stream>>>((const unsigned char*)fb8,
                                                   den_sum, num_sum);
    finalize_kernel<<<1, 256, 0, stream>>>(den_sum, num_sum, out);
}

// Round 10
// 117.544 us; speedup vs baseline: 1.2666x; 1.2666x over previous
//
#include <hip/hip_runtime.h>

#define NN 6144
#define DD 768
#define NB 48               // 6144 / 128 tile blocks per dim
#define NTILES 1176         // NB*(NB+1)/2 upper-triangular tiles
#define INV_T 14.285714285714286f
#define CMAX  14.285714285714286f

typedef int i32x4 __attribute__((ext_vector_type(4)));
typedef int i32x8 __attribute__((ext_vector_type(8)));
typedef float f32x4_t __attribute__((ext_vector_type(4)));

__device__ __forceinline__ void load_lds16(const void* g, void* l) {
    __builtin_amdgcn_global_load_lds((__attribute__((address_space(1))) void*)g,
                                     (__attribute__((address_space(3))) void*)l,
                                     16, 0, 0);
}

// Kernel 1: L2-normalize rows -> fp8 e4m3 (unit MX scale); zero den/num sums.
// One wave per row; 1536 blocks x 256 threads.
__global__ void norm_kernel(const float* __restrict__ feats,
                            unsigned int* __restrict__ fb8,   // 6144*192 uints
                            float* __restrict__ den_num) {    // [0..NN)=den, [NN..2NN)=num
    const int wid = threadIdx.x >> 6;
    const int lane = threadIdx.x & 63;
    const int row = blockIdx.x * 4 + wid;

    if (threadIdx.x < 8) den_num[blockIdx.x * 8 + threadIdx.x] = 0.0f;

    const float4* src = (const float4*)(feats + (size_t)row * DD);
    float4 v[3];
    float ss = 0.0f;
#pragma unroll
    for (int i = 0; i < 3; ++i) {
        v[i] = src[lane + i * 64];
        ss += v[i].x * v[i].x + v[i].y * v[i].y + v[i].z * v[i].z + v[i].w * v[i].w;
    }
#pragma unroll
    for (int m = 32; m >= 1; m >>= 1) ss += __shfl_xor(ss, m);
    const float sc = 1.0f / fmaxf(sqrtf(ss), 1e-12f);

#pragma unroll
    for (int i = 0; i < 3; ++i) {
        unsigned int w = 0;
        w = __builtin_amdgcn_cvt_pk_fp8_f32(v[i].x * sc, v[i].y * sc, w, 0);
        w = __builtin_amdgcn_cvt_pk_fp8_f32(v[i].z * sc, v[i].w * sc, w, 1);
        fb8[(size_t)row * 192 + lane + i * 64] = w;
    }
}

// Kernel 2: upper-triangular MX-fp8 MFMA Gram tiles + fused exp row/col sums.
// 1176 blocks (one 128x128 tile), 256 threads (2x2 waves of 64x64).
// REG-PREFETCH PIPELINE, single 32 KB LDS buffer: next tile's global loads
// issue into VGPRs before computing the current tile; the vmcnt wait lands
// at the post-compute ds_write, where ~750 cyc of MFMA already covered the
// ~300-400 cyc L2 latency. (r9's 2x32KB LDS dbuf was an ILLEGAL 64 KB
// request: runtime pads +512 B over the 64 KB/workgroup limit -> launch
// abort. r6's single-buffer chain exposed full load latency every iter:
// gemm ~41us vs ~7us compute model, all pipes <10%.)
// __launch_bounds__(256,2): 256-reg budget (need ~174 unified incl. 64
// AGPR); tighter caps spilled 185-344 MB (r3/r4). #pragma unroll 1: full
// unroll interleaves all iterations' fragments -> spill.
// NO fences / scoped atomics (r5: per-block L2 wb/inv sweep = 128us idle).
__global__ __launch_bounds__(256, 2) void gemm_expsum_kernel(
        const unsigned char* __restrict__ fb8,
        float* __restrict__ den_sum, float* __restrict__ num_sum) {
    __shared__ __align__(16) char sA[128 * 128];
    __shared__ __align__(16) char sB[128 * 128];

    // triangular index -> (bi, bj), bi <= bj
    int rem = blockIdx.x;
    int bi = 0, rowlen = NB;
    while (rem >= rowlen) { rem -= rowlen; rowlen--; bi++; }
    const int bj = bi + rem;
    const bool isdiag = (bi == bj);
    const bool neardiag = (bj - bi) <= 1;
    const int i0 = bi * 128;
    const int j0 = bj * 128;

    const int t = threadIdx.x;
    const int lane = t & 63;
    const int wid = t >> 6;
    const int wm = wid >> 1;  // wave row (0..1)
    const int wn = wid & 1;   // wave col (0..1)

    // staging: thread t -> row = t>>3 (+32/issue), 16B chunk (t&7)^(row&7)
    // LDS linear offset t*16 + issue*4096 (= row*128 + swizzled-chunk*16)
    const int srow = t >> 3;
    const int scb = ((t & 7) ^ (srow & 7)) * 16;
    const unsigned char* gA = fb8 + (size_t)(i0 + srow) * DD + scb;
    const unsigned char* gB = fb8 + (size_t)(j0 + srow) * DD + scb;
    const int ldsoff = wid * 1024;  // wave-uniform base for load_lds16

    f32x4_t acc[4][4];
    const f32x4_t zz = {0.0f, 0.0f, 0.0f, 0.0f};
#pragma unroll
    for (int mi = 0; mi < 4; ++mi)
#pragma unroll
        for (int ni = 0; ni < 4; ++ni) acc[mi][ni] = zz;

    const int q = lane >> 4;
    const int mrow = lane & 15;
    const int x7 = lane & 7;
    const int c0 = ((q << 1) ^ x7) << 4;        // chunk byte offset, k-half 0
    const int c1 = (((q << 1) | 1) ^ x7) << 4;  // k-half 1

    // prologue: stage tile 0 directly into LDS
#pragma unroll
    for (int i = 0; i < 4; ++i) {
        load_lds16(gA + (size_t)(i * 32) * DD, &sA[ldsoff + i * 4096]);
        load_lds16(gB + (size_t)(i * 32) * DD, &sB[ldsoff + i * 4096]);
    }
    __syncthreads();

#pragma unroll 1
    for (int kb = 0; kb < 6; ++kb) {
        // 1) prefetch next tile into registers (coalesced 16B/thread)
        i32x4 pfA[4], pfB[4];
        if (kb < 5) {
            const int kn = (kb + 1) * 128;
#pragma unroll
            for (int i = 0; i < 4; ++i) {
                pfA[i] = *(const i32x4*)(gA + (size_t)(i * 32) * DD + kn);
                pfB[i] = *(const i32x4*)(gB + (size_t)(i * 32) * DD + kn);
            }
        }

        // 2) compute current tile from LDS
        i32x8 af[4];
#pragma unroll
        for (int mi = 0; mi < 4; ++mi) {
            const char* p = sA + (wm * 64 + mi * 16 + mrow) * 128;
            i32x4 lo = *(const i32x4*)(p + c0);
            i32x4 hi = *(const i32x4*)(p + c1);
            af[mi] = __builtin_shufflevector(lo, hi, 0, 1, 2, 3, 4, 5, 6, 7);
        }
#pragma unroll
        for (int ni = 0; ni < 4; ++ni) {
            const char* p = sB + (wn * 64 + ni * 16 + mrow) * 128;
            i32x4 lo = *(const i32x4*)(p + c0);
            i32x4 hi = *(const i32x4*)(p + c1);
            i32x8 bf = __builtin_shufflevector(lo, hi, 0, 1, 2, 3, 4, 5, 6, 7);
#pragma unroll
            for (int mi = 0; mi < 4; ++mi)
                acc[mi][ni] = __builtin_amdgcn_mfma_scale_f32_16x16x128_f8f6f4(
                    af[mi], bf, acc[mi][ni], 0, 0,
                    0, 0x7F7F7F7F, 0, 0x7F7F7F7F);  // unit scales (E8M0=127)
        }

        // 3) all reads of the buffer done
        __syncthreads();

        // 4) write prefetched tile into the (single) buffer
        if (kb < 5) {
#pragma unroll
            for (int i = 0; i < 4; ++i) {
                *(i32x4*)(sA + t * 16 + i * 4096) = pfA[i];
                *(i32x4*)(sB + t * 16 + i * 4096) = pfB[i];
            }
        }
        __syncthreads();
    }

    // Epilogue. C/D layout: col=lane&15 (+ni*16), row=(lane>>4)*4+reg (+mi*16).
    const int colb = j0 + wn * 64 + mrow;
    const int rowb = i0 + wm * 64 + (q << 2);
    float cs[4] = {0.f, 0.f, 0.f, 0.f};
    float csn[4] = {0.f, 0.f, 0.f, 0.f};
#pragma unroll
    for (int mi = 0; mi < 4; ++mi) {
        float rsv[4] = {0.f, 0.f, 0.f, 0.f};
        float rsn[4] = {0.f, 0.f, 0.f, 0.f};
#pragma unroll
        for (int ni = 0; ni < 4; ++ni) {
            const int col = colb + ni * 16;
#pragma unroll
            for (int r = 0; r < 4; ++r) {
                const int row = rowb + mi * 16 + r;
                const float v = acc[mi][ni][r] * INV_T;
                float e = __expf(v - CMAX);
                if (isdiag && row == col) e = 0.0f;
                rsv[r] += e;
                cs[ni] += e;
                if (neardiag && (row / 3 == col / 3) && row != col) {
                    rsn[r] += e;
                    csn[ni] += e;
                }
            }
        }
#pragma unroll
        for (int r = 0; r < 4; ++r) {
            float v = rsv[r];
            v += __shfl_xor(v, 8);
            v += __shfl_xor(v, 4);
            v += __shfl_xor(v, 2);
            v += __shfl_xor(v, 1);
            if (mrow == 0) atomicAdd(&den_sum[rowb + mi * 16 + r], v);
        }
        if (neardiag) {
#pragma unroll
            for (int r = 0; r < 4; ++r) {
                float v = rsn[r];
                v += __shfl_xor(v, 8);
                v += __shfl_xor(v, 4);
                v += __shfl_xor(v, 2);
                v += __shfl_xor(v, 1);
                if (mrow == 0) atomicAdd(&num_sum[rowb + mi * 16 + r], v);
            }
        }
    }
    if (!isdiag) {
#pragma unroll
        for (int ni = 0; ni < 4; ++ni) {
            float v = cs[ni];
            v += __shfl_xor(v, 16);
            v += __shfl_xor(v, 32);
            if (q == 0) atomicAdd(&den_sum[colb + ni * 16], v);
        }
        if (neardiag) {
#pragma unroll
            for (int ni = 0; ni < 4; ++ni) {
                float v = csn[ni];
                v += __shfl_xor(v, 16);
                v += __shfl_xor(v, 32);
                if (q == 0) atomicAdd(&num_sum[colb + ni * 16], v);
            }
        }
    }
}

// Kernel 3: loss = mean(log(den) - log(num))  (CMAX cancels). Single block.
__global__ void finalize_kernel(const float* __restrict__ den_sum,
                                const float* __restrict__ num_sum,
                                float* __restrict__ out) {
    float local = 0.0f;
    for (int i = threadIdx.x; i < NN; i += 256) {
        local += logf(den_sum[i]) - logf(num_sum[i]);
    }
#pragma unroll
    for (int m = 32; m >= 1; m >>= 1) local += __shfl_xor(local, m);
    __shared__ float ws[4];
    if ((threadIdx.x & 63) == 0) ws[threadIdx.x >> 6] = local;
    __syncthreads();
    if (threadIdx.x == 0) out[0] = (ws[0] + ws[1] + ws[2] + ws[3]) / (float)NN;
}

extern "C" void kernel_launch(void* const* d_in, const int* in_sizes, int n_in,
                              void* d_out, int out_size, void* d_ws, size_t ws_size,
                              hipStream_t stream) {
    const float* feats = (const float*)d_in[0];
    float* out = (float*)d_out;

    char* ws = (char*)d_ws;
    unsigned int* fb8 = (unsigned int*)ws;                 // 6144*768 = 4718592 B
    float* den_num    = (float*)(ws + 4718592);            // 2*6144*4 B
    float* den_sum    = den_num;
    float* num_sum    = den_num + NN;

    norm_kernel<<<NN / 4, 256, 0, stream>>>(feats, fb8, den_num);
    gemm_expsum_kernel<<<NTILES, 256, 0, stream>>>((const unsigned char*)fb8,
                                                   den_sum, num_sum);
    finalize_kernel<<<1, 256, 0, stream>>>(den_sum, num_sum, out);
}

// Round 11
// 112.900 us; speedup vs baseline: 1.3187x; 1.0411x over previous
//
#include <hip/hip_runtime.h>

#define NN 6144
#define DD 768
#define NB 48               // 6144 / 128 tile blocks per dim
#define NTILES 1176         // NB*(NB+1)/2 upper-triangular tiles
#define INV_T 14.285714285714286f
#define CMAX  14.285714285714286f

typedef int i32x8 __attribute__((ext_vector_type(8)));
typedef float f32x4_t __attribute__((ext_vector_type(4)));

// fb8 blocked layout: addr(row,k) = ((rb*6+kc)*64 + q*16 + mrow)*32 + (k%32)
//   rb=row/16, mrow=row%16, kc=k/128, q=(k%128)/32.
// A 16x16x128 MFMA fragment (row-block rb, k-chunk kc) is then the 2048 B
// slab at ((rb*6+kc)*2048): lane (q*16+mrow) reads its 32 B at +lane*32 --
// ONE coalesced global_load_dwordx8 per fragment (r8's row-major direct
// loads hit 16 scattered rows per instruction -> 79.5us).

// Kernel 1: L2-normalize rows -> fp8 e4m3 in blocked layout; zero den/num.
// One wave per row; 1536 blocks x 256 threads.
__global__ void norm_kernel(const float* __restrict__ feats,
                            unsigned int* __restrict__ fb8,   // blocked, 6144*192 uints
                            float* __restrict__ den_num) {    // [0..NN)=den, [NN..2NN)=num
    const int wid = threadIdx.x >> 6;
    const int lane = threadIdx.x & 63;
    const int row = blockIdx.x * 4 + wid;

    if (threadIdx.x < 8) den_num[blockIdx.x * 8 + threadIdx.x] = 0.0f;

    const float4* src = (const float4*)(feats + (size_t)row * DD);
    float4 v[3];
    float ss = 0.0f;
#pragma unroll
    for (int i = 0; i < 3; ++i) {
        v[i] = src[lane + i * 64];
        ss += v[i].x * v[i].x + v[i].y * v[i].y + v[i].z * v[i].z + v[i].w * v[i].w;
    }
#pragma unroll
    for (int m = 32; m >= 1; m >>= 1) ss += __shfl_xor(ss, m);
    const float sc = 1.0f / fmaxf(sqrtf(ss), 1e-12f);

    const int rb = row >> 4;
    const int mrow = row & 15;
#pragma unroll
    for (int i = 0; i < 3; ++i) {
        unsigned int w = 0;
        w = __builtin_amdgcn_cvt_pk_fp8_f32(v[i].x * sc, v[i].y * sc, w, 0);
        w = __builtin_amdgcn_cvt_pk_fp8_f32(v[i].z * sc, v[i].w * sc, w, 1);
        // this uint covers row bytes k = (lane+i*64)*4 .. +3
        const int e = lane + i * 64;        // dword index within row (0..191)
        const int kc = e >> 5;              // /32 dwords = /128 bytes
        const int q = (e >> 3) & 3;         // 32-byte chunk within 128
        const int dw = e & 7;               // dword within 32-byte chunk
        fb8[(((size_t)rb * 6 + kc) * 64 + q * 16 + mrow) * 8 + dw] = w;
    }
}

// Kernel 2: upper-triangular MX-fp8 MFMA Gram tiles + fused exp row/col sums.
// 1176 blocks (one 128x128 tile), 256 threads (2x2 waves of 64x64).
// NO LDS, NO barriers: fragments load straight from the blocked fb8 layout
// (coalesced dwordx8, L2-resident 4.7 MB). Every LDS variant (r6/r7/r10)
// was barrier-serialized at 40-47us vs a 6-9us floor with all pipes <20%
// busy; independent waves can anti-phase and hide L2 latency.
// __launch_bounds__(256,2): ~150 unified regs incl 64 AGPR -> no spill
// (r3/r4 spilled under tighter caps). #pragma unroll 1: full unroll of the
// k-loop interleaves all iterations' fragments -> 185-344 MB scratch spill.
// NO fences / scoped atomics (r5: per-block L2 wb/inv sweep = 128us idle).
__global__ __launch_bounds__(256, 2) void gemm_expsum_kernel(
        const unsigned char* __restrict__ fb8,
        float* __restrict__ den_sum, float* __restrict__ num_sum) {
    // triangular index -> (bi, bj), bi <= bj
    int rem = blockIdx.x;
    int bi = 0, rowlen = NB;
    while (rem >= rowlen) { rem -= rowlen; rowlen--; bi++; }
    const int bj = bi + rem;
    const bool isdiag = (bi == bj);
    const bool neardiag = (bj - bi) <= 1;
    const int i0 = bi * 128;
    const int j0 = bj * 128;

    const int t = threadIdx.x;
    const int lane = t & 63;
    const int wid = t >> 6;
    const int wm = wid >> 1;  // wave row (0..1)
    const int wn = wid & 1;   // wave col (0..1)

    const int q = lane >> 4;
    const int mrow = lane & 15;

    // fragment slab bases: frag(rb,kc) at fb8 + ((rb*6+kc)*2048) + lane*32
    const int rbA0 = bi * 8 + wm * 4;
    const int rbB0 = bj * 8 + wn * 4;
    const unsigned char* pA = fb8 + (size_t)rbA0 * 6 * 2048 + lane * 32;
    const unsigned char* pB = fb8 + (size_t)rbB0 * 6 * 2048 + lane * 32;

    f32x4_t acc[4][4];
    const f32x4_t zz = {0.0f, 0.0f, 0.0f, 0.0f};
#pragma unroll
    for (int mi = 0; mi < 4; ++mi)
#pragma unroll
        for (int ni = 0; ni < 4; ++ni) acc[mi][ni] = zz;

#pragma unroll 1
    for (int kc = 0; kc < 6; ++kc) {
        i32x8 af[4], bf[4];
#pragma unroll
        for (int mi = 0; mi < 4; ++mi)
            af[mi] = *(const i32x8*)(pA + (size_t)(mi * 6 + kc) * 2048);
#pragma unroll
        for (int ni = 0; ni < 4; ++ni)
            bf[ni] = *(const i32x8*)(pB + (size_t)(ni * 6 + kc) * 2048);
#pragma unroll
        for (int ni = 0; ni < 4; ++ni)
#pragma unroll
            for (int mi = 0; mi < 4; ++mi)
                acc[mi][ni] = __builtin_amdgcn_mfma_scale_f32_16x16x128_f8f6f4(
                    af[mi], bf[ni], acc[mi][ni], 0, 0,
                    0, 0x7F7F7F7F, 0, 0x7F7F7F7F);  // unit scales (E8M0=127)
    }

    // Epilogue. C/D layout: col=lane&15 (+ni*16), row=(lane>>4)*4+reg (+mi*16).
    const int colb = j0 + wn * 64 + mrow;
    const int rowb = i0 + wm * 64 + (q << 2);
    float cs[4] = {0.f, 0.f, 0.f, 0.f};
    float csn[4] = {0.f, 0.f, 0.f, 0.f};
#pragma unroll
    for (int mi = 0; mi < 4; ++mi) {
        float rsv[4] = {0.f, 0.f, 0.f, 0.f};
        float rsn[4] = {0.f, 0.f, 0.f, 0.f};
#pragma unroll
        for (int ni = 0; ni < 4; ++ni) {
            const int col = colb + ni * 16;
#pragma unroll
            for (int r = 0; r < 4; ++r) {
                const int row = rowb + mi * 16 + r;
                const float v = acc[mi][ni][r] * INV_T;
                float e = __expf(v - CMAX);
                if (isdiag && row == col) e = 0.0f;
                rsv[r] += e;
                cs[ni] += e;
                if (neardiag && (row / 3 == col / 3) && row != col) {
                    rsn[r] += e;
                    csn[ni] += e;
                }
            }
        }
#pragma unroll
        for (int r = 0; r < 4; ++r) {
            float v = rsv[r];
            v += __shfl_xor(v, 8);
            v += __shfl_xor(v, 4);
            v += __shfl_xor(v, 2);
            v += __shfl_xor(v, 1);
            if (mrow == 0) atomicAdd(&den_sum[rowb + mi * 16 + r], v);
        }
        if (neardiag) {
#pragma unroll
            for (int r = 0; r < 4; ++r) {
                float v = rsn[r];
                v += __shfl_xor(v, 8);
                v += __shfl_xor(v, 4);
                v += __shfl_xor(v, 2);
                v += __shfl_xor(v, 1);
                if (mrow == 0) atomicAdd(&num_sum[rowb + mi * 16 + r], v);
            }
        }
    }
    if (!isdiag) {
#pragma unroll
        for (int ni = 0; ni < 4; ++ni) {
            float v = cs[ni];
            v += __shfl_xor(v, 16);
            v += __shfl_xor(v, 32);
            if (q == 0) atomicAdd(&den_sum[colb + ni * 16], v);
        }
        if (neardiag) {
#pragma unroll
            for (int ni = 0; ni < 4; ++ni) {
                float v = csn[ni];
                v += __shfl_xor(v, 16);
                v += __shfl_xor(v, 32);
                if (q == 0) atomicAdd(&num_sum[colb + ni * 16], v);
            }
        }
    }
}

// Kernel 3: loss = mean(log(den) - log(num))  (CMAX cancels). Single block.
__global__ void finalize_kernel(const float* __restrict__ den_sum,
                                const float* __restrict__ num_sum,
                                float* __restrict__ out) {
    float local = 0.0f;
    for (int i = threadIdx.x; i < NN; i += 256) {
        local += logf(den_sum[i]) - logf(num_sum[i]);
    }
#pragma unroll
    for (int m = 32; m >= 1; m >>= 1) local += __shfl_xor(local, m);
    __shared__ float ws[4];
    if ((threadIdx.x & 63) == 0) ws[threadIdx.x >> 6] = local;
    __syncthreads();
    if (threadIdx.x == 0) out[0] = (ws[0] + ws[1] + ws[2] + ws[3]) / (float)NN;
}

extern "C" void kernel_launch(void* const* d_in, const int* in_sizes, int n_in,
                              void* d_out, int out_size, void* d_ws, size_t ws_size,
                              hipStream_t stream) {
    const float* feats = (const float*)d_in[0];
    float* out = (float*)d_out;

    char* ws = (char*)d_ws;
    unsigned int* fb8 = (unsigned int*)ws;                 // 6144*768 = 4718592 B (blocked)
    float* den_num    = (float*)(ws + 4718592);            // 2*6144*4 B
    float* den_sum    = den_num;
    float* num_sum    = den_num + NN;

    norm_kernel<<<NN / 4, 256, 0, stream>>>(feats, fb8, den_num);
    gemm_expsum_kernel<<<NTILES, 256, 0, stream>>>((const unsigned char*)fb8,
                                                   den_sum, num_sum);
    finalize_kernel<<<1, 256, 0, stream>>>(den_sum, num_sum, out);
}